// Round 17
// baseline (398.402 us; speedup 1.0000x reference)
//
#include <hip/hip_runtime.h>
#include <stdint.h>

// ONNX NonMaxSuppression: B=8, N=16384, C=80, MAX_OUT=50
// MEGAKERNEL pipeline (memset 2.5KB + ONE kernel):
//   nms_mega: 2560 blocks (4 per (b,c)). Each block scans its quarter of the
//     lane's scores, writes a private key segment + count/total, then
//     fence + atomicAdd(done[bc]) election: the LAST-finishing block of each
//     lane proceeds straight into the verified walk (global->reg keys,
//     register bitonic sort, box gather, LAZY sorted walk) or the inline
//     slow path on overflow/exhaustion. Lanes whose scans finish early walk
//     while other lanes still scan -> no global drain between phases.
//   done[] zeroed per call via hipMemsetAsync (graph-capturable).
//   Slow path is LDS-slim (boxes decoded from keys, read from global) so the
//   megakernel keeps 8 blocks/CU occupancy.
// Fallbacks: monolithic kernel + gated slow (ws >= 2560B), else slow-for-all.

#define NMS_B 8
#define NMS_N 16384
#define NMS_C 80
#define NMS_MAX_OUT 50
#define NTHREADS 256
#define NLANES (NMS_B * NMS_C)

#define OPT_THR 0.98828125f  // = 1 - 192/16384 exactly; E[cnt]=192, sigma~13.8
#define FCAP 256
#define WMAX (FCAP / 64)     // 4 regs per lane in the register sort
#define SPLIT 4
#define SEG 120              // per-part capacity: E=48, sigma~6.9 -> +10 sigma
#define SCAN_N (NMS_N / SPLIT)

// slow (fallback) path
#define NBUCK 256
#define SCAP 1024
#define T_MIN 320

typedef unsigned long long u64;

// ws layout
#define WS_FLAGS  0
#define WS_DONE   (NLANES * 4)
#define WS_CNTS   (NLANES * 8)
#define WS_TOTALS (WS_CNTS + NLANES * SPLIT * 4)
#define WS_KEYS   (WS_TOTALS + NLANES * SPLIT * 4)
#define WS_NEED   ((size_t)WS_KEYS + (size_t)NLANES * SPLIT * SEG * 8)

__device__ __forceinline__ float iou_exact(float4 A, float areaA, float4 Bx) {
    float x1 = fmaxf(A.x, Bx.x);
    float y1 = fmaxf(A.y, Bx.y);
    float x2 = fminf(A.z, Bx.z);
    float y2 = fminf(A.w, Bx.w);
    float dx = fmaxf(__fsub_rn(x2, x1), 0.0f);
    float dy = fmaxf(__fsub_rn(y2, y1), 0.0f);
    if (!(dx > 0.0f && dy > 0.0f)) return 0.0f;   // inter==0 -> iou==0 exactly
    float inter = __fmul_rn(dx, dy);
    float areaB = __fmul_rn(__fsub_rn(Bx.z, Bx.x), __fsub_rn(Bx.w, Bx.y));
    float uni   = __fsub_rn(__fadd_rn(areaA, areaB), inter);
    return __fdiv_rn(inter, fmaxf(uni, 1e-9f));
}

__device__ __forceinline__ u64 umax64(u64 a, u64 b) { return a > b ? a : b; }
__device__ __forceinline__ u64 umin64(u64 a, u64 b) { return a < b ? a : b; }

__device__ __forceinline__ int bucketf(float s) {
    int v = (int)__float_as_uint(s) - 0x3F000000;
    v >>= 15;
    return v < 0 ? 0 : (v > 255 ? 255 : v);
}

// ---------------- verified slow path (round-2 structure), LDS-slim ----------------
// Boxes are decoded from keys and read from GLOBAL (cold path) so the shared
// footprint stays small. IoU inputs are value-identical to the r2-r16 version.
// Must be entered by ALL 256 threads of the block (contains __syncthreads).
template <bool OUT64>
__device__ __noinline__ void slow_body(
    const float* __restrict__ boxes,
    const float* __restrict__ scores,
    const int* __restrict__ p_maxout,
    const float* __restrict__ p_iou,
    const float* __restrict__ p_sthr,
    void* __restrict__ out_raw,
    int bc)
{
    __shared__ int    hist[NBUCK];
    __shared__ u64    key[SCAP];
    __shared__ float4 selbox[NMS_MAX_OUT];
    __shared__ u64    s_wmax[NTHREADS / 64];
    __shared__ u64    s_best;
    __shared__ int    s_cnt, s_cutLo, s_cutHi, s_rem, s_state;

    const int tid = threadIdx.x;
    const int b   = bc / NMS_C;
    const int c   = bc % NMS_C;

    const float score_thr = p_sthr[0];
    const float iou_thr   = p_iou[0];
    int maxo = p_maxout[0];
    if (maxo > NMS_MAX_OUT) maxo = NMS_MAX_OUT;
    if (maxo < 0) maxo = 0;

    int*       out32 = (int*)out_raw       + (size_t)bc * NMS_MAX_OUT * 3;
    long long* out64 = (long long*)out_raw + (size_t)bc * NMS_MAX_OUT * 3;
    for (int i = tid; i < NMS_MAX_OUT * 3; i += NTHREADS) {
        if (OUT64) out64[i] = -1LL; else out32[i] = -1;
    }

    const float*  sc      = scores + ((size_t)b * NMS_C + c) * NMS_N;
    const float4* sc4     = (const float4*)sc;
    const float4* boxes_b = (const float4*)(boxes + (size_t)b * NMS_N * 4);

    for (int i = tid; i < NBUCK; i += NTHREADS) hist[i] = 0;
    if (tid == 0) s_cnt = 0;
    __syncthreads();
    for (int i = tid; i < NMS_N / 4; i += NTHREADS) {
        float4 s4 = sc4[i];
        float ss[4] = {s4.x, s4.y, s4.z, s4.w};
        #pragma unroll
        for (int j = 0; j < 4; ++j)
            if (ss[j] > score_thr) atomicAdd(&hist[bucketf(ss[j])], 1);
    }
    __syncthreads();

    if (tid == 0) {
        int cum = 0, cut = NBUCK;
        for (int bk = NBUCK - 1; bk >= 0; --bk) {
            int h = hist[bk];
            if (cum > 0 && cum + h > SCAP) break;
            cum += h; cut = bk;
            if (cum >= T_MIN) break;
        }
        s_cutLo = cut; s_cutHi = NBUCK - 1;
        int rem = 0;
        for (int bk = 0; bk < cut; ++bk) rem += hist[bk];
        s_rem = rem;
    }
    __syncthreads();

    auto compact = [&](int lo, int hi) {
        for (int i = tid; i < NMS_N / 4; i += NTHREADS) {
            float4 s4 = sc4[i];
            float ss[4] = {s4.x, s4.y, s4.z, s4.w};
            #pragma unroll
            for (int j = 0; j < 4; ++j) {
                float s = ss[j];
                if (s > score_thr) {
                    int bk = bucketf(s);
                    if (bk >= lo && bk <= hi) {
                        int n = i * 4 + j;
                        int p = atomicAdd(&s_cnt, 1);
                        if (p < SCAP) {
                            key[p] = ((u64)__float_as_uint(s) << 24)
                                   | ((u64)(NMS_N - 1 - n) << 10)
                                   | (u64)p;
                        }
                    }
                }
            }
        }
    };
    compact(s_cutLo, s_cutHi);
    __syncthreads();

    int t = 0;
    while (t < maxo) {
        int m = s_cnt; if (m > SCAP) m = SCAP;
        u64 lmax = 0ull;
        for (int i = tid; i < m; i += NTHREADS) {
            u64 k = key[i];
            if (k > lmax) lmax = k;
        }
        #pragma unroll
        for (int off = 32; off > 0; off >>= 1) {
            u64 o = __shfl_down(lmax, off);
            if (o > lmax) lmax = o;
        }
        if ((tid & 63) == 0) s_wmax[tid >> 6] = lmax;
        __syncthreads();
        if (tid == 0) {
            u64 best = s_wmax[0];
            #pragma unroll
            for (int w = 1; w < NTHREADS / 64; ++w)
                if (s_wmax[w] > best) best = s_wmax[w];
            s_best = best;
            if (best) {
                int slot = (int)(best & 0x3FFull);
                int n    = NMS_N - 1 - (int)((best >> 10) & 0x3FFFull);
                key[slot] = 0ull;
                if (OUT64) {
                    out64[t * 3 + 0] = (long long)b;
                    out64[t * 3 + 1] = (long long)c;
                    out64[t * 3 + 2] = (long long)n;
                } else {
                    out32[t * 3 + 0] = b;
                    out32[t * 3 + 1] = c;
                    out32[t * 3 + 2] = n;
                }
                selbox[t] = boxes_b[n];      // same value cbox held before
                s_state = 0;
            } else if (s_rem == 0) {
                s_state = 2;
            } else {
                int hiB = s_cutLo - 1;
                int cum = 0, cut = hiB + 1;
                for (int bk = hiB; bk >= 0; --bk) {
                    int h = hist[bk];
                    if (cum > 0 && cum + h > SCAP) break;
                    cum += h; cut = bk;
                    if (cum >= T_MIN) break;
                }
                s_cutLo = cut; s_cutHi = hiB;
                int rem = 0;
                for (int bk = 0; bk < cut; ++bk) rem += hist[bk];
                s_rem = rem;
                s_cnt = 0;
                s_state = 1;
            }
        }
        __syncthreads();

        if (s_state == 2) break;

        if (s_state == 0) {
            const float4 A = selbox[t];
            const float areaA = __fmul_rn(__fsub_rn(A.z, A.x), __fsub_rn(A.w, A.y));
            int m0 = s_cnt; if (m0 > SCAP) m0 = SCAP;
            for (int i = tid; i < m0; i += NTHREADS) {
                u64 k = key[i];
                if (!k) continue;
                int nn = NMS_N - 1 - (int)((k >> 10) & 0x3FFFull);
                if (iou_exact(A, areaA, boxes_b[nn]) > iou_thr) key[i] = 0ull;
            }
            __syncthreads();
            ++t;
        } else {
            compact(s_cutLo, s_cutHi);
            __syncthreads();
            int m2 = s_cnt; if (m2 > SCAP) m2 = SCAP;
            for (int i = tid; i < m2; i += NTHREADS) {
                u64 k = key[i];
                if (!k) continue;
                int nn = NMS_N - 1 - (int)((k >> 10) & 0x3FFFull);
                float4 Bx = boxes_b[nn];
                for (int j = 0; j < t; ++j) {
                    float4 A = selbox[j];
                    float areaA = __fmul_rn(__fsub_rn(A.z, A.x), __fsub_rn(A.w, A.y));
                    if (iou_exact(A, areaA, Bx) > iou_thr) { key[i] = 0ull; break; }
                }
            }
            __syncthreads();
        }
    }
}

// ---------------- megakernel: scan + election + walk/slow ----------------
template <bool OUT64>
__global__ __launch_bounds__(NTHREADS) void nms_mega(
    const float* __restrict__ boxes,
    const float* __restrict__ scores,
    const int* __restrict__ p_maxout,
    const float* __restrict__ p_iou,
    const float* __restrict__ p_sthr,
    void* __restrict__ out_raw,
    int* __restrict__ cnts,
    int* __restrict__ totals,
    u64* __restrict__ keys,
    int* __restrict__ done)
{
    __shared__ u64 lkey[SEG];
    __shared__ int lcnt, ltot, s_elected;
    __shared__ int    sn_[FCAP];
    __shared__ float4 sbox[FCAP];
    __shared__ int    s_need_slow;

    const int bid  = blockIdx.x;
    const int bc   = bid / SPLIT;
    const int part = bid % SPLIT;
    const int tid  = threadIdx.x;
    const int b    = bc / NMS_C;
    const int c    = bc % NMS_C;

    // ---- scan phase (r13-proven) ----
    const float4* sc4 = (const float4*)(scores + (size_t)bc * NMS_N + part * SCAN_N);
    float4 av[4];
    #pragma unroll
    for (int u = 0; u < 4; ++u) av[u] = sc4[u * NTHREADS + tid];
    __builtin_amdgcn_sched_barrier(0);       // all 4 loads in flight

    if (tid == 0) { lcnt = 0; ltot = 0; }
    __syncthreads();

    const float sthr = p_sthr[0];
    int lt = 0;
    #pragma unroll
    for (int u = 0; u < 4; ++u) {
        const int i = u * NTHREADS + tid;
        float ss[4] = {av[u].x, av[u].y, av[u].z, av[u].w};
        #pragma unroll
        for (int j = 0; j < 4; ++j) {
            float s = ss[j];
            bool cand = (s > sthr);
            lt += cand ? 1 : 0;
            if (cand && s >= OPT_THR) {      // rare
                int n = part * SCAN_N + i * 4 + j;
                int p = atomicAdd(&lcnt, 1);
                if (p < SEG)
                    lkey[p] = ((u64)__float_as_uint(s) << 32)
                            | ((u64)(NMS_N - 1 - n) << 18);
            }
        }
    }
    #pragma unroll
    for (int off = 32; off > 0; off >>= 1) lt += __shfl_down(lt, off, 64);
    if ((tid & 63) == 0) atomicAdd(&ltot, lt);
    __syncthreads();

    const int cnt = lcnt;
    if (tid == 0) {
        cnts[bc * SPLIT + part]   = cnt;     // may exceed SEG -> handled later
        totals[bc * SPLIT + part] = ltot;
    }
    {
        u64* kseg = keys + ((size_t)bc * SPLIT + part) * SEG;
        const int mm = (cnt < SEG) ? cnt : SEG;
        if (tid < mm) kseg[tid] = lkey[tid];
    }

    // ---- election: last-finishing block of this lane continues ----
    __threadfence();                         // release our segment stores
    __syncthreads();                         // all threads' stores + fences done
    if (tid == 0) {
        int old = atomicAdd(&done[bc], 1);   // device-scope
        s_elected = (old == SPLIT - 1) ? 1 : 0;
    }
    __syncthreads();
    if (!s_elected) return;
    __threadfence();                         // acquire other parts' stores

    // ---- walk phase (r16-fused, verified) ----
    const float iou_thr = p_iou[0];
    int maxo = p_maxout[0];
    if (maxo > NMS_MAX_OUT) maxo = NMS_MAX_OUT;
    if (maxo < 0) maxo = 0;

    int*       out32 = (int*)out_raw       + (size_t)bc * NMS_MAX_OUT * 3;
    long long* out64 = (long long*)out_raw + (size_t)bc * NMS_MAX_OUT * 3;
    for (int i = tid; i < NMS_MAX_OUT * 3; i += NTHREADS) {
        if (OUT64) out64[i] = -1LL; else out32[i] = -1;
    }

    const int c0 = cnts[bc * SPLIT + 0], c1 = cnts[bc * SPLIT + 1];
    const int c2 = cnts[bc * SPLIT + 2], c3 = cnts[bc * SPLIT + 3];
    const int tt = totals[bc * SPLIT + 0] + totals[bc * SPLIT + 1]
                 + totals[bc * SPLIT + 2] + totals[bc * SPLIT + 3];
    const int o1 = c0, o2 = c0 + c1, o3 = c0 + c1 + c2;
    const int m  = o3 + c3;
    const bool bad = (c0 > SEG) | (c1 > SEG) | (c2 > SEG) | (c3 > SEG) | (m > FCAP);
    if (bad) {                               // uniform: whole block -> slow
        slow_body<OUT64>(boxes, scores, p_maxout, p_iou, p_sthr, out_raw, bc);
        return;
    }
    const int rem = tt - m;

    if (tid < 64) {
        const int lane = tid;

        const u64* kb = keys + (size_t)bc * SPLIT * SEG;
        u64 v[WMAX];
        #pragma unroll
        for (int q = 0; q < WMAX; ++q) {
            const int idx = q * 64 + lane;
            int p, base;
            if (idx < o1)      { p = 0; base = 0;  }
            else if (idx < o2) { p = 1; base = o1; }
            else if (idx < o3) { p = 2; base = o2; }
            else               { p = 3; base = o3; }
            v[q] = (idx < m) ? kb[(size_t)p * SEG + (idx - base)] : 0ull;
        }

        #define STAGE_SHFL(J, D0, D1, D2, D3) {                                   \
            const bool low_ = ((lane & (J)) == 0);                                \
            { u64 o = __shfl_xor(v[0], (J), 64); bool d_ = (D0);                  \
              v[0] = (low_ == d_) ? umax64(v[0], o) : umin64(v[0], o); }          \
            { u64 o = __shfl_xor(v[1], (J), 64); bool d_ = (D1);                  \
              v[1] = (low_ == d_) ? umax64(v[1], o) : umin64(v[1], o); }          \
            { u64 o = __shfl_xor(v[2], (J), 64); bool d_ = (D2);                  \
              v[2] = (low_ == d_) ? umax64(v[2], o) : umin64(v[2], o); }          \
            { u64 o = __shfl_xor(v[3], (J), 64); bool d_ = (D3);                  \
              v[3] = (low_ == d_) ? umax64(v[3], o) : umin64(v[3], o); }          \
        }

        #pragma unroll
        for (int k = 2; k <= 32; k <<= 1) {
            #pragma unroll
            for (int j = k >> 1; j > 0; j >>= 1) {
                const bool dd = ((lane & k) == 0);
                STAGE_SHFL(j, dd, dd, dd, dd);
            }
        }
        #pragma unroll
        for (int j = 32; j > 0; j >>= 1) STAGE_SHFL(j, true, false, true, false);
        { u64 a = v[0], bb = v[1]; v[0] = umax64(a, bb); v[1] = umin64(a, bb); }
        { u64 a = v[2], bb = v[3]; v[2] = umin64(a, bb); v[3] = umax64(a, bb); }
        #pragma unroll
        for (int j = 32; j > 0; j >>= 1) STAGE_SHFL(j, true, true, false, false);
        { u64 a = v[0], bb = v[2]; v[0] = umax64(a, bb); v[2] = umin64(a, bb); }
        { u64 a = v[1], bb = v[3]; v[1] = umax64(a, bb); v[3] = umin64(a, bb); }
        { u64 a = v[0], bb = v[1]; v[0] = umax64(a, bb); v[1] = umin64(a, bb); }
        { u64 a = v[2], bb = v[3]; v[2] = umax64(a, bb); v[3] = umin64(a, bb); }
        #pragma unroll
        for (int j = 32; j > 0; j >>= 1) STAGE_SHFL(j, true, true, true, true);
        #undef STAGE_SHFL

        const float4* boxes_b = (const float4*)(boxes + (size_t)b * NMS_N * 4);
        #pragma unroll
        for (int q = 0; q < WMAX; ++q) {
            const int r = q * 64 + lane;
            const int n = NMS_N - 1 - (int)((v[q] >> 18) & 0x3FFFull);  // pad-safe
            sn_[r] = n;
            sbox[r] = boxes_b[n];
        }
        // single wave: per-wave LDS is in-order; no barrier needed

        float selx = 1e30f, sely = 1e30f, selz = -1e30f, selw = -1e30f, sela = 0.0f;
        int t = 0, r = 0;
        float4 cand = (m > 0) ? sbox[0] : make_float4(0.f, 0.f, 0.f, 0.f);

        while (t < maxo && r < m) {
            const int rn = (r + 1 < FCAP) ? (r + 1) : r;
            const float4 nxt = sbox[rn];     // prefetch next rank under the IoU

            const float areaC = __fmul_rn(__fsub_rn(cand.z, cand.x),
                                          __fsub_rn(cand.w, cand.y));
            float x1 = fmaxf(selx, cand.x);
            float y1 = fmaxf(sely, cand.y);
            float x2 = fminf(selz, cand.z);
            float y2 = fminf(selw, cand.w);
            float dx = fmaxf(__fsub_rn(x2, x1), 0.0f);
            float dy = fmaxf(__fsub_rn(y2, y1), 0.0f);
            bool sup = false;
            if (dx > 0.0f && dy > 0.0f) {    // inter==0 -> iou==0 exact skip
                float inter = __fmul_rn(dx, dy);
                float uni   = __fsub_rn(__fadd_rn(sela, areaC), inter);
                sup = __fdiv_rn(inter, fmaxf(uni, 1e-9f)) > iou_thr;
            }
            if (__ballot(sup) == 0ull) {     // no prior pick suppresses -> pick
                if (lane == 0) {
                    const int n = sn_[r];
                    if (OUT64) {
                        out64[t * 3 + 0] = (long long)b;
                        out64[t * 3 + 1] = (long long)c;
                        out64[t * 3 + 2] = (long long)n;
                    } else {
                        out32[t * 3 + 0] = b;
                        out32[t * 3 + 1] = c;
                        out32[t * 3 + 2] = n;
                    }
                }
                if (lane == t) {             // latch pick-t into this lane
                    selx = cand.x; sely = cand.y; selz = cand.z; selw = cand.w;
                    sela = areaC;
                }
                ++t;
            }
            ++r;
            cand = nxt;
        }
        if (lane == 0) s_need_slow = (t < maxo && rem > 0) ? 1 : 0;
    }
    __syncthreads();                         // waves 1..3 park here
    if (s_need_slow)
        slow_body<OUT64>(boxes, scores, p_maxout, p_iou, p_sthr, out_raw, bc);
}

// ---------------- monolithic fallback (mid-ws; r14-r16 verified) ----------------
template <bool OUT64>
__global__ __launch_bounds__(NTHREADS, 4) void nms_fast_mono(
    const float* __restrict__ boxes,
    const float* __restrict__ scores,
    const int* __restrict__ p_maxout,
    const float* __restrict__ p_iou,
    const float* __restrict__ p_sthr,
    void* __restrict__ out_raw,
    int* __restrict__ flags)
{
    __shared__ u64    skey[FCAP];
    __shared__ int    sn_[FCAP];
    __shared__ float4 sbox[FCAP];
    __shared__ int    s_cnt, s_total;

    const int tid = threadIdx.x;
    const int bc  = blockIdx.x;
    const int b   = bc / NMS_C;
    const int c   = bc % NMS_C;

    const float4* sc4     = (const float4*)(scores + ((size_t)b * NMS_C + c) * NMS_N);
    const float4* boxes_b = (const float4*)(boxes + (size_t)b * NMS_N * 4);

    float4 av[16];
    #pragma unroll
    for (int u = 0; u < 16; ++u) av[u] = sc4[u * NTHREADS + tid];
    __builtin_amdgcn_sched_barrier(0);

    const float score_thr = p_sthr[0];
    const float iou_thr   = p_iou[0];
    int maxo = p_maxout[0];
    if (maxo > NMS_MAX_OUT) maxo = NMS_MAX_OUT;
    if (maxo < 0) maxo = 0;

    int*       out32 = (int*)out_raw       + (size_t)bc * NMS_MAX_OUT * 3;
    long long* out64 = (long long*)out_raw + (size_t)bc * NMS_MAX_OUT * 3;
    for (int i = tid; i < NMS_MAX_OUT * 3; i += NTHREADS) {
        if (OUT64) out64[i] = -1LL; else out32[i] = -1;
    }

    if (tid == 0) { s_cnt = 0; s_total = 0; }
    __syncthreads();

    int local_total = 0;
    #pragma unroll
    for (int u = 0; u < 16; ++u) {
        const int i = u * NTHREADS + tid;
        float ss[4] = {av[u].x, av[u].y, av[u].z, av[u].w};
        #pragma unroll
        for (int j = 0; j < 4; ++j) {
            float s = ss[j];
            bool cand = (s > score_thr);
            local_total += cand ? 1 : 0;
            if (cand && s >= OPT_THR) {
                int n = i * 4 + j;
                int p = atomicAdd(&s_cnt, 1);
                if (p < FCAP) {
                    skey[p] = ((u64)__float_as_uint(s) << 32)
                            | ((u64)(NMS_N - 1 - n) << 18);
                }
            }
        }
    }
    atomicAdd(&s_total, local_total);
    __syncthreads();

    const int cn = s_cnt;
    const int m  = (cn < FCAP) ? cn : FCAP;
    if (cn > FCAP) {
        if (tid == 0) flags[bc] = 1;
        return;
    }
    if (tid >= 64) return;
    const int lane = tid;
    const int rem  = s_total - cn;

    u64 v[WMAX];
    #pragma unroll
    for (int q = 0; q < WMAX; ++q) {
        const int idx = q * 64 + lane;
        v[q] = (idx < m) ? skey[idx] : 0ull;
    }

    #define STAGE_SHFL(J, D0, D1, D2, D3) {                                       \
        const bool low_ = ((lane & (J)) == 0);                                    \
        { u64 o = __shfl_xor(v[0], (J), 64); bool d_ = (D0);                      \
          v[0] = (low_ == d_) ? umax64(v[0], o) : umin64(v[0], o); }              \
        { u64 o = __shfl_xor(v[1], (J), 64); bool d_ = (D1);                      \
          v[1] = (low_ == d_) ? umax64(v[1], o) : umin64(v[1], o); }              \
        { u64 o = __shfl_xor(v[2], (J), 64); bool d_ = (D2);                      \
          v[2] = (low_ == d_) ? umax64(v[2], o) : umin64(v[2], o); }              \
        { u64 o = __shfl_xor(v[3], (J), 64); bool d_ = (D3);                      \
          v[3] = (low_ == d_) ? umax64(v[3], o) : umin64(v[3], o); }              \
    }

    #pragma unroll
    for (int k = 2; k <= 32; k <<= 1) {
        #pragma unroll
        for (int j = k >> 1; j > 0; j >>= 1) {
            const bool dd = ((lane & k) == 0);
            STAGE_SHFL(j, dd, dd, dd, dd);
        }
    }
    #pragma unroll
    for (int j = 32; j > 0; j >>= 1) STAGE_SHFL(j, true, false, true, false);
    { u64 a = v[0], bb = v[1]; v[0] = umax64(a, bb); v[1] = umin64(a, bb); }
    { u64 a = v[2], bb = v[3]; v[2] = umin64(a, bb); v[3] = umax64(a, bb); }
    #pragma unroll
    for (int j = 32; j > 0; j >>= 1) STAGE_SHFL(j, true, true, false, false);
    { u64 a = v[0], bb = v[2]; v[0] = umax64(a, bb); v[2] = umin64(a, bb); }
    { u64 a = v[1], bb = v[3]; v[1] = umax64(a, bb); v[3] = umin64(a, bb); }
    { u64 a = v[0], bb = v[1]; v[0] = umax64(a, bb); v[1] = umin64(a, bb); }
    { u64 a = v[2], bb = v[3]; v[2] = umax64(a, bb); v[3] = umin64(a, bb); }
    #pragma unroll
    for (int j = 32; j > 0; j >>= 1) STAGE_SHFL(j, true, true, true, true);
    #undef STAGE_SHFL

    #pragma unroll
    for (int q = 0; q < WMAX; ++q) {
        const int r = q * 64 + lane;
        const int n = NMS_N - 1 - (int)((v[q] >> 18) & 0x3FFFull);
        sn_[r] = n;
        sbox[r] = boxes_b[n];
    }

    float selx = 1e30f, sely = 1e30f, selz = -1e30f, selw = -1e30f, sela = 0.0f;
    int t = 0, r = 0, need_slow = 0;
    float4 cand = (m > 0) ? sbox[0] : make_float4(0.f, 0.f, 0.f, 0.f);

    while (t < maxo && r < m) {
        const int rn = (r + 1 < FCAP) ? (r + 1) : r;
        const float4 nxt = sbox[rn];
        const float areaC = __fmul_rn(__fsub_rn(cand.z, cand.x),
                                      __fsub_rn(cand.w, cand.y));
        float x1 = fmaxf(selx, cand.x);
        float y1 = fmaxf(sely, cand.y);
        float x2 = fminf(selz, cand.z);
        float y2 = fminf(selw, cand.w);
        float dx = fmaxf(__fsub_rn(x2, x1), 0.0f);
        float dy = fmaxf(__fsub_rn(y2, y1), 0.0f);
        bool sup = false;
        if (dx > 0.0f && dy > 0.0f) {
            float inter = __fmul_rn(dx, dy);
            float uni   = __fsub_rn(__fadd_rn(sela, areaC), inter);
            sup = __fdiv_rn(inter, fmaxf(uni, 1e-9f)) > iou_thr;
        }
        if (__ballot(sup) == 0ull) {
            if (lane == 0) {
                const int n = sn_[r];
                if (OUT64) {
                    out64[t * 3 + 0] = (long long)b;
                    out64[t * 3 + 1] = (long long)c;
                    out64[t * 3 + 2] = (long long)n;
                } else {
                    out32[t * 3 + 0] = b;
                    out32[t * 3 + 1] = c;
                    out32[t * 3 + 2] = n;
                }
            }
            if (lane == t) {
                selx = cand.x; sely = cand.y; selz = cand.z; selw = cand.w;
                sela = areaC;
            }
            ++t;
        }
        ++r;
        cand = nxt;
    }
    if (t < maxo && rem > 0) need_slow = 1;
    if (lane == 0) flags[bc] = need_slow;
}

// ---- standalone gated slow kernel (for fallback launch configs) ----
template <bool OUT64>
__global__ __launch_bounds__(NTHREADS) void nms_slow(
    const float* __restrict__ boxes,
    const float* __restrict__ scores,
    const int* __restrict__ p_maxout,
    const float* __restrict__ p_iou,
    const float* __restrict__ p_sthr,
    void* __restrict__ out_raw,
    const int* __restrict__ flags)
{
    const int bc = blockIdx.x;
    if (flags && flags[bc] == 0) return;     // uniform exit before any barrier
    slow_body<OUT64>(boxes, scores, p_maxout, p_iou, p_sthr, out_raw, bc);
}

extern "C" void kernel_launch(void* const* d_in, const int* in_sizes, int n_in,
                              void* d_out, int out_size, void* d_ws, size_t ws_size,
                              hipStream_t stream) {
    const float* boxes  = (const float*)d_in[0];
    const float* scores = (const float*)d_in[1];
    const int*   p_maxo = (const int*)d_in[2];
    const float* p_iou  = (const float*)d_in[3];
    const float* p_sthr = (const float*)d_in[4];

    const dim3 block(NTHREADS);
    const bool out64 = (out_size == NLANES * NMS_MAX_OUT * 3 * 2);

    char* ws = (char*)d_ws;
    int*  flags  = (int*)(ws + WS_FLAGS);
    int*  done   = (int*)(ws + WS_DONE);
    int*  cnts   = (int*)(ws + WS_CNTS);
    int*  totals = (int*)(ws + WS_TOTALS);
    u64*  keys   = (u64*)(ws + WS_KEYS);

    if (ws_size >= WS_NEED) {
        hipMemsetAsync(done, 0, NLANES * sizeof(int), stream);
        if (out64) {
            hipLaunchKernelGGL(nms_mega<true>, dim3(NLANES * SPLIT), block, 0, stream,
                               boxes, scores, p_maxo, p_iou, p_sthr, d_out,
                               cnts, totals, keys, done);
        } else {
            hipLaunchKernelGGL(nms_mega<false>, dim3(NLANES * SPLIT), block, 0, stream,
                               boxes, scores, p_maxo, p_iou, p_sthr, d_out,
                               cnts, totals, keys, done);
        }
    } else if (ws_size >= (size_t)NLANES * sizeof(int)) {
        if (out64) {
            hipLaunchKernelGGL(nms_fast_mono<true>, dim3(NLANES), block, 0, stream,
                               boxes, scores, p_maxo, p_iou, p_sthr, d_out, flags);
            hipLaunchKernelGGL(nms_slow<true>, dim3(NLANES), block, 0, stream,
                               boxes, scores, p_maxo, p_iou, p_sthr, d_out, flags);
        } else {
            hipLaunchKernelGGL(nms_fast_mono<false>, dim3(NLANES), block, 0, stream,
                               boxes, scores, p_maxo, p_iou, p_sthr, d_out, flags);
            hipLaunchKernelGGL(nms_slow<false>, dim3(NLANES), block, 0, stream,
                               boxes, scores, p_maxo, p_iou, p_sthr, d_out, flags);
        }
    } else {
        if (out64) {
            hipLaunchKernelGGL(nms_slow<true>, dim3(NLANES), block, 0, stream,
                               boxes, scores, p_maxo, p_iou, p_sthr, d_out, (const int*)nullptr);
        } else {
            hipLaunchKernelGGL(nms_slow<false>, dim3(NLANES), block, 0, stream,
                               boxes, scores, p_maxo, p_iou, p_sthr, d_out, (const int*)nullptr);
        }
    }
}

// Round 18
// 38.283 us; speedup vs baseline: 10.4067x; 10.4067x over previous
//
#include <hip/hip_runtime.h>
#include <stdint.h>

// ONNX NonMaxSuppression: B=8, N=16384, C=80, MAX_OUT=50
// TWO-launch pipeline (r16-verified, 38.3us):
//   nms_scan: 4 blocks per (b,c) stream scores, compact candidates >= OPT_THR
//             into private ws segments + non-atomic count/total.
//   nms_fused (256 thr): uniform prefix-sum of counts; if overflow -> run the
//             VERIFIED slow path inline. Else wave 0 does global->reg key
//             load, register bitonic sort, box gather, LAZY sorted walk;
//             waves 1-3 park at one barrier; exhaustion -> inline slow path.
// NOTE r17 lesson: a fused single-kernel "election" variant (threadfence +
// cross-XCD done[] atomics) ran 10x SLOWER (66 GB/s, VALUBusy 2%) — device
// scope fences + cross-XCD reads defeat the L2. Kernel-boundary visibility
// (two launches) is the cheap way to pass data between block sets.
// Fallbacks: monolithic kernel + gated slow (ws >= 2560B), else slow-for-all.

#define NMS_B 8
#define NMS_N 16384
#define NMS_C 80
#define NMS_MAX_OUT 50
#define NTHREADS 256
#define NLANES (NMS_B * NMS_C)

#define OPT_THR 0.98828125f  // = 1 - 192/16384 exactly; E[cnt]=192, sigma~13.8
#define FCAP 256
#define WMAX (FCAP / 64)     // 4 regs per lane in the register sort
#define SPLIT 4
#define SEG 120              // per-part capacity: E=48, sigma~6.9 -> +10 sigma
#define SCAN_N (NMS_N / SPLIT)

// slow (fallback) path
#define NBUCK 256
#define SCAP 1024
#define T_MIN 320

typedef unsigned long long u64;

// ws layout (flags kept for the mid-ws fallback path only)
#define WS_FLAGS  0
#define WS_CNTS   (NLANES * 4)
#define WS_TOTALS (WS_CNTS + NLANES * SPLIT * 4)
#define WS_KEYS   (WS_TOTALS + NLANES * SPLIT * 4)
#define WS_NEED   ((size_t)WS_KEYS + (size_t)NLANES * SPLIT * SEG * 8)

__device__ __forceinline__ float iou_exact(float4 A, float areaA, float4 Bx) {
    float x1 = fmaxf(A.x, Bx.x);
    float y1 = fmaxf(A.y, Bx.y);
    float x2 = fminf(A.z, Bx.z);
    float y2 = fminf(A.w, Bx.w);
    float dx = fmaxf(__fsub_rn(x2, x1), 0.0f);
    float dy = fmaxf(__fsub_rn(y2, y1), 0.0f);
    if (!(dx > 0.0f && dy > 0.0f)) return 0.0f;   // inter==0 -> iou==0 exactly
    float inter = __fmul_rn(dx, dy);
    float areaB = __fmul_rn(__fsub_rn(Bx.z, Bx.x), __fsub_rn(Bx.w, Bx.y));
    float uni   = __fsub_rn(__fadd_rn(areaA, areaB), inter);
    return __fdiv_rn(inter, fmaxf(uni, 1e-9f));
}

__device__ __forceinline__ u64 umax64(u64 a, u64 b) { return a > b ? a : b; }
__device__ __forceinline__ u64 umin64(u64 a, u64 b) { return a < b ? a : b; }

__device__ __forceinline__ int bucketf(float s) {
    int v = (int)__float_as_uint(s) - 0x3F000000;
    v >>= 15;
    return v < 0 ? 0 : (v > 255 ? 255 : v);
}

// ---------------- verified slow path (round-2 structure) as device fn ----------------
// Must be entered by ALL 256 threads of the block (contains __syncthreads).
template <bool OUT64>
__device__ __noinline__ void slow_body(
    const float* __restrict__ boxes,
    const float* __restrict__ scores,
    const int* __restrict__ p_maxout,
    const float* __restrict__ p_iou,
    const float* __restrict__ p_sthr,
    void* __restrict__ out_raw,
    int bc)
{
    __shared__ int    hist[NBUCK];
    __shared__ u64    key[SCAP];
    __shared__ float4 cbox[SCAP];
    __shared__ float4 selbox[NMS_MAX_OUT];
    __shared__ u64    s_wmax[NTHREADS / 64];
    __shared__ u64    s_best;
    __shared__ int    s_cnt, s_cutLo, s_cutHi, s_rem, s_state;

    const int tid = threadIdx.x;
    const int b   = bc / NMS_C;
    const int c   = bc % NMS_C;

    const float score_thr = p_sthr[0];
    const float iou_thr   = p_iou[0];
    int maxo = p_maxout[0];
    if (maxo > NMS_MAX_OUT) maxo = NMS_MAX_OUT;
    if (maxo < 0) maxo = 0;

    int*       out32 = (int*)out_raw       + (size_t)bc * NMS_MAX_OUT * 3;
    long long* out64 = (long long*)out_raw + (size_t)bc * NMS_MAX_OUT * 3;
    for (int i = tid; i < NMS_MAX_OUT * 3; i += NTHREADS) {
        if (OUT64) out64[i] = -1LL; else out32[i] = -1;
    }

    const float*  sc      = scores + ((size_t)b * NMS_C + c) * NMS_N;
    const float4* sc4     = (const float4*)sc;
    const float4* boxes_b = (const float4*)(boxes + (size_t)b * NMS_N * 4);

    for (int i = tid; i < NBUCK; i += NTHREADS) hist[i] = 0;
    if (tid == 0) s_cnt = 0;
    __syncthreads();
    for (int i = tid; i < NMS_N / 4; i += NTHREADS) {
        float4 s4 = sc4[i];
        float ss[4] = {s4.x, s4.y, s4.z, s4.w};
        #pragma unroll
        for (int j = 0; j < 4; ++j)
            if (ss[j] > score_thr) atomicAdd(&hist[bucketf(ss[j])], 1);
    }
    __syncthreads();

    if (tid == 0) {
        int cum = 0, cut = NBUCK;
        for (int bk = NBUCK - 1; bk >= 0; --bk) {
            int h = hist[bk];
            if (cum > 0 && cum + h > SCAP) break;
            cum += h; cut = bk;
            if (cum >= T_MIN) break;
        }
        s_cutLo = cut; s_cutHi = NBUCK - 1;
        int rem = 0;
        for (int bk = 0; bk < cut; ++bk) rem += hist[bk];
        s_rem = rem;
    }
    __syncthreads();

    auto compact = [&](int lo, int hi) {
        for (int i = tid; i < NMS_N / 4; i += NTHREADS) {
            float4 s4 = sc4[i];
            float ss[4] = {s4.x, s4.y, s4.z, s4.w};
            #pragma unroll
            for (int j = 0; j < 4; ++j) {
                float s = ss[j];
                if (s > score_thr) {
                    int bk = bucketf(s);
                    if (bk >= lo && bk <= hi) {
                        int n = i * 4 + j;
                        int p = atomicAdd(&s_cnt, 1);
                        if (p < SCAP) {
                            key[p] = ((u64)__float_as_uint(s) << 24)
                                   | ((u64)(NMS_N - 1 - n) << 10)
                                   | (u64)p;
                            cbox[p] = boxes_b[n];
                        }
                    }
                }
            }
        }
    };
    compact(s_cutLo, s_cutHi);
    __syncthreads();

    int t = 0;
    while (t < maxo) {
        int m = s_cnt; if (m > SCAP) m = SCAP;
        u64 lmax = 0ull;
        for (int i = tid; i < m; i += NTHREADS) {
            u64 k = key[i];
            if (k > lmax) lmax = k;
        }
        #pragma unroll
        for (int off = 32; off > 0; off >>= 1) {
            u64 o = __shfl_down(lmax, off);
            if (o > lmax) lmax = o;
        }
        if ((tid & 63) == 0) s_wmax[tid >> 6] = lmax;
        __syncthreads();
        if (tid == 0) {
            u64 best = s_wmax[0];
            #pragma unroll
            for (int w = 1; w < NTHREADS / 64; ++w)
                if (s_wmax[w] > best) best = s_wmax[w];
            s_best = best;
            if (best) {
                int slot = (int)(best & 0x3FFull);
                int n    = NMS_N - 1 - (int)((best >> 10) & 0x3FFFull);
                key[slot] = 0ull;
                if (OUT64) {
                    out64[t * 3 + 0] = (long long)b;
                    out64[t * 3 + 1] = (long long)c;
                    out64[t * 3 + 2] = (long long)n;
                } else {
                    out32[t * 3 + 0] = b;
                    out32[t * 3 + 1] = c;
                    out32[t * 3 + 2] = n;
                }
                selbox[t] = cbox[slot];
                s_state = 0;
            } else if (s_rem == 0) {
                s_state = 2;
            } else {
                int hiB = s_cutLo - 1;
                int cum = 0, cut = hiB + 1;
                for (int bk = hiB; bk >= 0; --bk) {
                    int h = hist[bk];
                    if (cum > 0 && cum + h > SCAP) break;
                    cum += h; cut = bk;
                    if (cum >= T_MIN) break;
                }
                s_cutLo = cut; s_cutHi = hiB;
                int rem = 0;
                for (int bk = 0; bk < cut; ++bk) rem += hist[bk];
                s_rem = rem;
                s_cnt = 0;
                s_state = 1;
            }
        }
        __syncthreads();

        if (s_state == 2) break;

        if (s_state == 0) {
            const float4 A = selbox[t];
            const float areaA = __fmul_rn(__fsub_rn(A.z, A.x), __fsub_rn(A.w, A.y));
            int m0 = s_cnt; if (m0 > SCAP) m0 = SCAP;
            for (int i = tid; i < m0; i += NTHREADS) {
                u64 k = key[i];
                if (!k) continue;
                if (iou_exact(A, areaA, cbox[i]) > iou_thr) key[i] = 0ull;
            }
            __syncthreads();
            ++t;
        } else {
            compact(s_cutLo, s_cutHi);
            __syncthreads();
            int m2 = s_cnt; if (m2 > SCAP) m2 = SCAP;
            for (int i = tid; i < m2; i += NTHREADS) {
                u64 k = key[i];
                if (!k) continue;
                float4 Bx = cbox[i];
                for (int j = 0; j < t; ++j) {
                    float4 A = selbox[j];
                    float areaA = __fmul_rn(__fsub_rn(A.z, A.x), __fsub_rn(A.w, A.y));
                    if (iou_exact(A, areaA, Bx) > iou_thr) { key[i] = 0ull; break; }
                }
            }
            __syncthreads();
        }
    }
}

// ---------------- phase 1: contention-free parallel scan ----------------
__global__ __launch_bounds__(NTHREADS) void nms_scan(
    const float* __restrict__ scores,
    const float* __restrict__ p_sthr,
    int* __restrict__ cnts,
    int* __restrict__ totals,
    u64* __restrict__ keys)
{
    __shared__ u64 lkey[SEG];
    __shared__ int lcnt, ltot;

    const int bid  = blockIdx.x;
    const int bc   = bid / SPLIT;
    const int part = bid % SPLIT;
    const int tid  = threadIdx.x;

    const float4* sc4 = (const float4*)(scores + (size_t)bc * NMS_N + part * SCAN_N);
    float4 av[4];
    #pragma unroll
    for (int u = 0; u < 4; ++u) av[u] = sc4[u * NTHREADS + tid];
    __builtin_amdgcn_sched_barrier(0);       // all 4 loads in flight

    if (tid == 0) { lcnt = 0; ltot = 0; }
    __syncthreads();

    const float sthr = p_sthr[0];
    int lt = 0;
    #pragma unroll
    for (int u = 0; u < 4; ++u) {
        const int i = u * NTHREADS + tid;
        float ss[4] = {av[u].x, av[u].y, av[u].z, av[u].w};
        #pragma unroll
        for (int j = 0; j < 4; ++j) {
            float s = ss[j];
            bool cand = (s > sthr);
            lt += cand ? 1 : 0;
            if (cand && s >= OPT_THR) {      // rare
                int n = part * SCAN_N + i * 4 + j;
                int p = atomicAdd(&lcnt, 1);
                if (p < SEG)
                    lkey[p] = ((u64)__float_as_uint(s) << 32)
                            | ((u64)(NMS_N - 1 - n) << 18);
            }
        }
    }
    #pragma unroll
    for (int off = 32; off > 0; off >>= 1) lt += __shfl_down(lt, off, 64);
    if ((tid & 63) == 0) atomicAdd(&ltot, lt);
    __syncthreads();

    const int cnt = lcnt;
    if (tid == 0) {
        cnts[bc * SPLIT + part]   = cnt;     // may exceed SEG -> handled later
        totals[bc * SPLIT + part] = ltot;
    }
    u64* kseg = keys + ((size_t)bc * SPLIT + part) * SEG;
    const int mm = (cnt < SEG) ? cnt : SEG;
    if (tid < mm) kseg[tid] = lkey[tid];
}

// ---------------- phase 2: fused sort + LAZY walk + inline slow ----------------
template <bool OUT64>
__global__ __launch_bounds__(NTHREADS) void nms_fused(
    const float* __restrict__ boxes,
    const float* __restrict__ scores,
    const int* __restrict__ p_maxout,
    const float* __restrict__ p_iou,
    const float* __restrict__ p_sthr,
    void* __restrict__ out_raw,
    const int* __restrict__ cnts,
    const int* __restrict__ totals,
    const u64* __restrict__ keys)
{
    __shared__ int    sn_[FCAP];
    __shared__ float4 sbox[FCAP];
    __shared__ int    s_need_slow;

    const int tid  = threadIdx.x;
    const int bc   = blockIdx.x;
    const int b    = bc / NMS_C;
    const int c    = bc % NMS_C;

    const float iou_thr = p_iou[0];
    int maxo = p_maxout[0];
    if (maxo > NMS_MAX_OUT) maxo = NMS_MAX_OUT;
    if (maxo < 0) maxo = 0;

    int*       out32 = (int*)out_raw       + (size_t)bc * NMS_MAX_OUT * 3;
    long long* out64 = (long long*)out_raw + (size_t)bc * NMS_MAX_OUT * 3;
    for (int i = tid; i < NMS_MAX_OUT * 3; i += NTHREADS) {
        if (OUT64) out64[i] = -1LL; else out32[i] = -1;
    }

    // uniform loads (same address across lanes -> broadcast)
    const int c0 = cnts[bc * SPLIT + 0], c1 = cnts[bc * SPLIT + 1];
    const int c2 = cnts[bc * SPLIT + 2], c3 = cnts[bc * SPLIT + 3];
    const int tt = totals[bc * SPLIT + 0] + totals[bc * SPLIT + 1]
                 + totals[bc * SPLIT + 2] + totals[bc * SPLIT + 3];
    const int o1 = c0, o2 = c0 + c1, o3 = c0 + c1 + c2;
    const int m  = o3 + c3;
    const bool bad = (c0 > SEG) | (c1 > SEG) | (c2 > SEG) | (c3 > SEG) | (m > FCAP);
    if (bad) {                               // uniform: whole block -> slow
        slow_body<OUT64>(boxes, scores, p_maxout, p_iou, p_sthr, out_raw, bc);
        return;
    }
    const int rem = tt - m;

    if (tid < 64) {
        const int lane = tid;

        // ---- keys straight global -> register (part-select per reg) ----
        const u64* kb = keys + (size_t)bc * SPLIT * SEG;
        u64 v[WMAX];
        #pragma unroll
        for (int q = 0; q < WMAX; ++q) {
            const int idx = q * 64 + lane;
            int p, base;
            if (idx < o1)      { p = 0; base = 0;  }
            else if (idx < o2) { p = 1; base = o1; }
            else if (idx < o3) { p = 2; base = o2; }
            else               { p = 3; base = o3; }
            v[q] = (idx < m) ? kb[(size_t)p * SEG + (idx - base)] : 0ull;
        }

        // ---- register bitonic sort (desc), 256 elems, i = q*64+lane ----
        #define STAGE_SHFL(J, D0, D1, D2, D3) {                                   \
            const bool low_ = ((lane & (J)) == 0);                                \
            { u64 o = __shfl_xor(v[0], (J), 64); bool d_ = (D0);                  \
              v[0] = (low_ == d_) ? umax64(v[0], o) : umin64(v[0], o); }          \
            { u64 o = __shfl_xor(v[1], (J), 64); bool d_ = (D1);                  \
              v[1] = (low_ == d_) ? umax64(v[1], o) : umin64(v[1], o); }          \
            { u64 o = __shfl_xor(v[2], (J), 64); bool d_ = (D2);                  \
              v[2] = (low_ == d_) ? umax64(v[2], o) : umin64(v[2], o); }          \
            { u64 o = __shfl_xor(v[3], (J), 64); bool d_ = (D3);                  \
              v[3] = (low_ == d_) ? umax64(v[3], o) : umin64(v[3], o); }          \
        }

        #pragma unroll
        for (int k = 2; k <= 32; k <<= 1) {
            #pragma unroll
            for (int j = k >> 1; j > 0; j >>= 1) {
                const bool dd = ((lane & k) == 0);
                STAGE_SHFL(j, dd, dd, dd, dd);
            }
        }
        #pragma unroll
        for (int j = 32; j > 0; j >>= 1) STAGE_SHFL(j, true, false, true, false);
        { u64 a = v[0], bb = v[1]; v[0] = umax64(a, bb); v[1] = umin64(a, bb); }
        { u64 a = v[2], bb = v[3]; v[2] = umin64(a, bb); v[3] = umax64(a, bb); }
        #pragma unroll
        for (int j = 32; j > 0; j >>= 1) STAGE_SHFL(j, true, true, false, false);
        { u64 a = v[0], bb = v[2]; v[0] = umax64(a, bb); v[2] = umin64(a, bb); }
        { u64 a = v[1], bb = v[3]; v[1] = umax64(a, bb); v[3] = umin64(a, bb); }
        { u64 a = v[0], bb = v[1]; v[0] = umax64(a, bb); v[1] = umin64(a, bb); }
        { u64 a = v[2], bb = v[3]; v[2] = umax64(a, bb); v[3] = umin64(a, bb); }
        #pragma unroll
        for (int j = 32; j > 0; j >>= 1) STAGE_SHFL(j, true, true, true, true);
        #undef STAGE_SHFL

        // ---- gather boxes by rank; publish n + box per rank to LDS ----
        const float4* boxes_b = (const float4*)(boxes + (size_t)b * NMS_N * 4);
        #pragma unroll
        for (int q = 0; q < WMAX; ++q) {
            const int r = q * 64 + lane;
            const int n = NMS_N - 1 - (int)((v[q] >> 18) & 0x3FFFull);  // pad-safe
            sn_[r] = n;
            sbox[r] = boxes_b[n];
        }
        // single wave: per-wave LDS is in-order; no barrier needed

        // ---- LAZY sorted walk: lane l holds pick-l's box ----
        float selx = 1e30f, sely = 1e30f, selz = -1e30f, selw = -1e30f, sela = 0.0f;
        int t = 0, r = 0;
        float4 cand = (m > 0) ? sbox[0] : make_float4(0.f, 0.f, 0.f, 0.f);

        while (t < maxo && r < m) {
            const int rn = (r + 1 < FCAP) ? (r + 1) : r;
            const float4 nxt = sbox[rn];     // prefetch next rank under the IoU

            const float areaC = __fmul_rn(__fsub_rn(cand.z, cand.x),
                                          __fsub_rn(cand.w, cand.y));
            float x1 = fmaxf(selx, cand.x);
            float y1 = fmaxf(sely, cand.y);
            float x2 = fminf(selz, cand.z);
            float y2 = fminf(selw, cand.w);
            float dx = fmaxf(__fsub_rn(x2, x1), 0.0f);
            float dy = fmaxf(__fsub_rn(y2, y1), 0.0f);
            bool sup = false;
            if (dx > 0.0f && dy > 0.0f) {    // inter==0 -> iou==0 exact skip
                float inter = __fmul_rn(dx, dy);
                float uni   = __fsub_rn(__fadd_rn(sela, areaC), inter);
                sup = __fdiv_rn(inter, fmaxf(uni, 1e-9f)) > iou_thr;
            }
            if (__ballot(sup) == 0ull) {     // no prior pick suppresses -> pick
                if (lane == 0) {
                    const int n = sn_[r];
                    if (OUT64) {
                        out64[t * 3 + 0] = (long long)b;
                        out64[t * 3 + 1] = (long long)c;
                        out64[t * 3 + 2] = (long long)n;
                    } else {
                        out32[t * 3 + 0] = b;
                        out32[t * 3 + 1] = c;
                        out32[t * 3 + 2] = n;
                    }
                }
                if (lane == t) {             // latch pick-t into this lane
                    selx = cand.x; sely = cand.y; selz = cand.z; selw = cand.w;
                    sela = areaC;
                }
                ++t;
            }
            ++r;
            cand = nxt;
        }
        if (lane == 0) s_need_slow = (t < maxo && rem > 0) ? 1 : 0;
    }
    __syncthreads();                         // waves 1..3 park here
    if (s_need_slow)
        slow_body<OUT64>(boxes, scores, p_maxout, p_iou, p_sthr, out_raw, bc);
}

// ---------------- monolithic fallback (mid-ws; r14/r15-verified) ----------------
template <bool OUT64>
__global__ __launch_bounds__(NTHREADS, 4) void nms_fast_mono(
    const float* __restrict__ boxes,
    const float* __restrict__ scores,
    const int* __restrict__ p_maxout,
    const float* __restrict__ p_iou,
    const float* __restrict__ p_sthr,
    void* __restrict__ out_raw,
    int* __restrict__ flags)
{
    __shared__ u64    skey[FCAP];
    __shared__ int    sn_[FCAP];
    __shared__ float4 sbox[FCAP];
    __shared__ int    s_cnt, s_total;

    const int tid = threadIdx.x;
    const int bc  = blockIdx.x;
    const int b   = bc / NMS_C;
    const int c   = bc % NMS_C;

    const float4* sc4     = (const float4*)(scores + ((size_t)b * NMS_C + c) * NMS_N);
    const float4* boxes_b = (const float4*)(boxes + (size_t)b * NMS_N * 4);

    float4 av[16];
    #pragma unroll
    for (int u = 0; u < 16; ++u) av[u] = sc4[u * NTHREADS + tid];
    __builtin_amdgcn_sched_barrier(0);

    const float score_thr = p_sthr[0];
    const float iou_thr   = p_iou[0];
    int maxo = p_maxout[0];
    if (maxo > NMS_MAX_OUT) maxo = NMS_MAX_OUT;
    if (maxo < 0) maxo = 0;

    int*       out32 = (int*)out_raw       + (size_t)bc * NMS_MAX_OUT * 3;
    long long* out64 = (long long*)out_raw + (size_t)bc * NMS_MAX_OUT * 3;
    for (int i = tid; i < NMS_MAX_OUT * 3; i += NTHREADS) {
        if (OUT64) out64[i] = -1LL; else out32[i] = -1;
    }

    if (tid == 0) { s_cnt = 0; s_total = 0; }
    __syncthreads();

    int local_total = 0;
    #pragma unroll
    for (int u = 0; u < 16; ++u) {
        const int i = u * NTHREADS + tid;
        float ss[4] = {av[u].x, av[u].y, av[u].z, av[u].w};
        #pragma unroll
        for (int j = 0; j < 4; ++j) {
            float s = ss[j];
            bool cand = (s > score_thr);
            local_total += cand ? 1 : 0;
            if (cand && s >= OPT_THR) {
                int n = i * 4 + j;
                int p = atomicAdd(&s_cnt, 1);
                if (p < FCAP) {
                    skey[p] = ((u64)__float_as_uint(s) << 32)
                            | ((u64)(NMS_N - 1 - n) << 18);
                }
            }
        }
    }
    atomicAdd(&s_total, local_total);
    __syncthreads();

    const int cn = s_cnt;
    const int m  = (cn < FCAP) ? cn : FCAP;
    if (cn > FCAP) {
        if (tid == 0) flags[bc] = 1;
        return;
    }
    if (tid >= 64) return;
    const int lane = tid;
    const int rem  = s_total - cn;

    u64 v[WMAX];
    #pragma unroll
    for (int q = 0; q < WMAX; ++q) {
        const int idx = q * 64 + lane;
        v[q] = (idx < m) ? skey[idx] : 0ull;
    }

    #define STAGE_SHFL(J, D0, D1, D2, D3) {                                       \
        const bool low_ = ((lane & (J)) == 0);                                    \
        { u64 o = __shfl_xor(v[0], (J), 64); bool d_ = (D0);                      \
          v[0] = (low_ == d_) ? umax64(v[0], o) : umin64(v[0], o); }              \
        { u64 o = __shfl_xor(v[1], (J), 64); bool d_ = (D1);                      \
          v[1] = (low_ == d_) ? umax64(v[1], o) : umin64(v[1], o); }              \
        { u64 o = __shfl_xor(v[2], (J), 64); bool d_ = (D2);                      \
          v[2] = (low_ == d_) ? umax64(v[2], o) : umin64(v[2], o); }              \
        { u64 o = __shfl_xor(v[3], (J), 64); bool d_ = (D3);                      \
          v[3] = (low_ == d_) ? umax64(v[3], o) : umin64(v[3], o); }              \
    }

    #pragma unroll
    for (int k = 2; k <= 32; k <<= 1) {
        #pragma unroll
        for (int j = k >> 1; j > 0; j >>= 1) {
            const bool dd = ((lane & k) == 0);
            STAGE_SHFL(j, dd, dd, dd, dd);
        }
    }
    #pragma unroll
    for (int j = 32; j > 0; j >>= 1) STAGE_SHFL(j, true, false, true, false);
    { u64 a = v[0], bb = v[1]; v[0] = umax64(a, bb); v[1] = umin64(a, bb); }
    { u64 a = v[2], bb = v[3]; v[2] = umin64(a, bb); v[3] = umax64(a, bb); }
    #pragma unroll
    for (int j = 32; j > 0; j >>= 1) STAGE_SHFL(j, true, true, false, false);
    { u64 a = v[0], bb = v[2]; v[0] = umax64(a, bb); v[2] = umin64(a, bb); }
    { u64 a = v[1], bb = v[3]; v[1] = umax64(a, bb); v[3] = umin64(a, bb); }
    { u64 a = v[0], bb = v[1]; v[0] = umax64(a, bb); v[1] = umin64(a, bb); }
    { u64 a = v[2], bb = v[3]; v[2] = umax64(a, bb); v[3] = umin64(a, bb); }
    #pragma unroll
    for (int j = 32; j > 0; j >>= 1) STAGE_SHFL(j, true, true, true, true);
    #undef STAGE_SHFL

    #pragma unroll
    for (int q = 0; q < WMAX; ++q) {
        const int r = q * 64 + lane;
        const int n = NMS_N - 1 - (int)((v[q] >> 18) & 0x3FFFull);
        sn_[r] = n;
        sbox[r] = boxes_b[n];
    }

    float selx = 1e30f, sely = 1e30f, selz = -1e30f, selw = -1e30f, sela = 0.0f;
    int t = 0, r = 0, need_slow = 0;
    float4 cand = (m > 0) ? sbox[0] : make_float4(0.f, 0.f, 0.f, 0.f);

    while (t < maxo && r < m) {
        const int rn = (r + 1 < FCAP) ? (r + 1) : r;
        const float4 nxt = sbox[rn];
        const float areaC = __fmul_rn(__fsub_rn(cand.z, cand.x),
                                      __fsub_rn(cand.w, cand.y));
        float x1 = fmaxf(selx, cand.x);
        float y1 = fmaxf(sely, cand.y);
        float x2 = fminf(selz, cand.z);
        float y2 = fminf(selw, cand.w);
        float dx = fmaxf(__fsub_rn(x2, x1), 0.0f);
        float dy = fmaxf(__fsub_rn(y2, y1), 0.0f);
        bool sup = false;
        if (dx > 0.0f && dy > 0.0f) {
            float inter = __fmul_rn(dx, dy);
            float uni   = __fsub_rn(__fadd_rn(sela, areaC), inter);
            sup = __fdiv_rn(inter, fmaxf(uni, 1e-9f)) > iou_thr;
        }
        if (__ballot(sup) == 0ull) {
            if (lane == 0) {
                const int n = sn_[r];
                if (OUT64) {
                    out64[t * 3 + 0] = (long long)b;
                    out64[t * 3 + 1] = (long long)c;
                    out64[t * 3 + 2] = (long long)n;
                } else {
                    out32[t * 3 + 0] = b;
                    out32[t * 3 + 1] = c;
                    out32[t * 3 + 2] = n;
                }
            }
            if (lane == t) {
                selx = cand.x; sely = cand.y; selz = cand.z; selw = cand.w;
                sela = areaC;
            }
            ++t;
        }
        ++r;
        cand = nxt;
    }
    if (t < maxo && rem > 0) need_slow = 1;
    if (lane == 0) flags[bc] = need_slow;
}

// ---- standalone gated slow kernel (for fallback launch configs) ----
template <bool OUT64>
__global__ __launch_bounds__(NTHREADS) void nms_slow(
    const float* __restrict__ boxes,
    const float* __restrict__ scores,
    const int* __restrict__ p_maxout,
    const float* __restrict__ p_iou,
    const float* __restrict__ p_sthr,
    void* __restrict__ out_raw,
    const int* __restrict__ flags)
{
    const int bc = blockIdx.x;
    if (flags && flags[bc] == 0) return;     // uniform exit before any barrier
    slow_body<OUT64>(boxes, scores, p_maxout, p_iou, p_sthr, out_raw, bc);
}

extern "C" void kernel_launch(void* const* d_in, const int* in_sizes, int n_in,
                              void* d_out, int out_size, void* d_ws, size_t ws_size,
                              hipStream_t stream) {
    const float* boxes  = (const float*)d_in[0];
    const float* scores = (const float*)d_in[1];
    const int*   p_maxo = (const int*)d_in[2];
    const float* p_iou  = (const float*)d_in[3];
    const float* p_sthr = (const float*)d_in[4];

    const dim3 block(NTHREADS);
    const bool out64 = (out_size == NLANES * NMS_MAX_OUT * 3 * 2);

    char* ws = (char*)d_ws;
    int*  flags  = (int*)(ws + WS_FLAGS);
    int*  cnts   = (int*)(ws + WS_CNTS);
    int*  totals = (int*)(ws + WS_TOTALS);
    u64*  keys   = (u64*)(ws + WS_KEYS);

    if (ws_size >= WS_NEED) {
        hipLaunchKernelGGL(nms_scan, dim3(NLANES * SPLIT), block, 0, stream,
                           scores, p_sthr, cnts, totals, keys);
        if (out64) {
            hipLaunchKernelGGL(nms_fused<true>, dim3(NLANES), block, 0, stream,
                               boxes, scores, p_maxo, p_iou, p_sthr, d_out,
                               cnts, totals, keys);
        } else {
            hipLaunchKernelGGL(nms_fused<false>, dim3(NLANES), block, 0, stream,
                               boxes, scores, p_maxo, p_iou, p_sthr, d_out,
                               cnts, totals, keys);
        }
    } else if (ws_size >= (size_t)NLANES * sizeof(int)) {
        if (out64) {
            hipLaunchKernelGGL(nms_fast_mono<true>, dim3(NLANES), block, 0, stream,
                               boxes, scores, p_maxo, p_iou, p_sthr, d_out, flags);
            hipLaunchKernelGGL(nms_slow<true>, dim3(NLANES), block, 0, stream,
                               boxes, scores, p_maxo, p_iou, p_sthr, d_out, flags);
        } else {
            hipLaunchKernelGGL(nms_fast_mono<false>, dim3(NLANES), block, 0, stream,
                               boxes, scores, p_maxo, p_iou, p_sthr, d_out, flags);
            hipLaunchKernelGGL(nms_slow<false>, dim3(NLANES), block, 0, stream,
                               boxes, scores, p_maxo, p_iou, p_sthr, d_out, flags);
        }
    } else {
        if (out64) {
            hipLaunchKernelGGL(nms_slow<true>, dim3(NLANES), block, 0, stream,
                               boxes, scores, p_maxo, p_iou, p_sthr, d_out, (const int*)nullptr);
        } else {
            hipLaunchKernelGGL(nms_slow<false>, dim3(NLANES), block, 0, stream,
                               boxes, scores, p_maxo, p_iou, p_sthr, d_out, (const int*)nullptr);
        }
    }
}